// Round 2
// 993.148 us; speedup vs baseline: 2.3244x; 2.3244x over previous
//
#include <hip/hip_runtime.h>
#include <math.h>

// WindowAttention fused kernel, MFMA bf16-split (fp32-accurate) version.
// One block per window: 8192 blocks x 512 threads (8 waves), 1 block/CU (LDS-bound).
//
// All matmuls run on v_mfma_f32_16x16x32_bf16 with every fp32 operand split
// into hi+lo bf16 (3 MFMAs per product => ~2^-16 relative error, fp32-class).
// Tiles: M(tokens) padded 49->64 (4 tiles of 16).
//
// Fragment conventions (consistent sigma: both A and B use the same slot->k
// map, so any HW intra-lane k-order cancels in the dot product):
//   A: row = lane&15,  slot(g=lane>>4, j) -> k = 8*g + j
//   B: col = lane&15,  same slot map
//   D: col = lane&15,  row = 4*(lane>>4)+reg   [guide-verified m89/m91]
// Each fragment "unit" in LDS = 64 lanes x 16B = 1KB contiguous (hi), +1KB (lo).
//
// LDS map (132096 B total):
//   XU  [ 32KB]  x-frags (qkv GEMM A)  -> reused as u-frags (proj GEMM A)
//   Qr  [ 32KB]  q-frags (scores A)    -> reused as P-hi frags (PV A)
//   Kr  [ 32KB]  k-frags (scores B)    -> reused as P-lo frags (PV A)
//   Vr  [ 32KB]  v-frags (PV B)
//   inv [  1KB]  per-row 1/softmax-sum

namespace {
constexpr int N  = 49;
constexpr int C  = 128;
constexpr int NT = 512;
constexpr float SCALE = 0.17677669529663687f;  // 32^-0.5

typedef short bf16x8 __attribute__((ext_vector_type(8)));  // 8 bf16, 4 VGPR
typedef float f32x4  __attribute__((ext_vector_type(4)));  // 4 f32 acc
}

__device__ __forceinline__ ushort bf16_rne(float f) {
    unsigned int u = __builtin_bit_cast(unsigned int, f);
    unsigned int r = u + 0x7FFFu + ((u >> 16) & 1u);
    return (ushort)(r >> 16);
}
__device__ __forceinline__ float bf16_to_f(ushort h) {
    unsigned int u = ((unsigned int)h) << 16;
    return __builtin_bit_cast(float, u);
}
__device__ __forceinline__ void split2(float x, ushort& hi, ushort& lo) {
    hi = bf16_rne(x);
    lo = bf16_rne(x - bf16_to_f(hi));
}
__device__ __forceinline__ f32x4 mfma16(bf16x8 a, bf16x8 b, f32x4 c) {
    return __builtin_amdgcn_mfma_f32_16x16x32_bf16(a, b, c, 0, 0, 0);
}

__global__ __launch_bounds__(NT, 2) void win_attn(
    const float* __restrict__ x,         // [B,49,128]
    const float* __restrict__ qkv_w,     // [384,128]
    const float* __restrict__ proj_w,    // [128,128]
    const float* __restrict__ proj_b,    // [128]
    const float* __restrict__ table,     // [169,4]
    const float* __restrict__ mask,      // [nW,49,49]
    const int*   __restrict__ pos_index, // [49,49]
    float* __restrict__ out,             // [B,49,128]
    int nW)
{
    __shared__ __align__(16) unsigned char smem[132096];
    unsigned char* const XU = smem;            // 32KB
    unsigned char* const Qr = smem + 32768;    // 32KB
    unsigned char* const Kr = smem + 65536;    // 32KB
    unsigned char* const Vr = smem + 98304;    // 32KB
    float* const inv_s = (float*)(smem + 131072);  // 256 f32

    const int tid  = threadIdx.x;
    const int blk  = blockIdx.x;
    const int lane = tid & 63;
    const int wid  = tid >> 6;
    const int lr   = lane & 15;
    const int lg   = lane >> 4;
    const f32x4 fz = {0.f, 0.f, 0.f, 0.f};

    // ---- Phase 0: x -> A-frags (bf16 hi/lo), rows 49..63 zero-padded ----
    {
        const float* xb = x + (size_t)blk * (N * C);
        #pragma unroll
        for (int it = 0; it < 2; ++it) {
            const int slot = tid + it * NT;   // 0..1023 = (n 0..63) x (chunk 0..15)
            const int n  = slot >> 4;
            const int cc = slot & 15;         // 8-float chunk: c = cc*8 = 32*s + 8*g
            const int s  = cc >> 2;
            const int g  = cc & 3;
            unsigned int h32[4], l32[4];
            if (n < N) {
                const float4 f0 = *(const float4*)(xb + n * C + cc * 8);
                const float4 f1 = *(const float4*)(xb + n * C + cc * 8 + 4);
                const float f[8] = {f0.x, f0.y, f0.z, f0.w, f1.x, f1.y, f1.z, f1.w};
                ushort hh[8], ll[8];
                #pragma unroll
                for (int j = 0; j < 8; ++j) split2(f[j], hh[j], ll[j]);
                #pragma unroll
                for (int j = 0; j < 4; ++j) {
                    h32[j] = (unsigned int)hh[2*j] | ((unsigned int)hh[2*j+1] << 16);
                    l32[j] = (unsigned int)ll[2*j] | ((unsigned int)ll[2*j+1] << 16);
                }
            } else {
                #pragma unroll
                for (int j = 0; j < 4; ++j) { h32[j] = 0u; l32[j] = 0u; }
            }
            unsigned char* p = XU + ((n >> 4) * 4 + s) * 2048 + ((n & 15) + 16 * g) * 16;
            *(uint4*)p          = make_uint4(h32[0], h32[1], h32[2], h32[3]);
            *(uint4*)(p + 1024) = make_uint4(l32[0], l32[1], l32[2], l32[3]);
        }
    }
    __syncthreads();

    // ---- Phase 1: qkv GEMM [64x128]x[128x384]; D scattered into q/k/v frags ----
    // Wave owns 3 column-tiles: nt = wid, wid+8, wid+16. t-loop kept rolled to
    // bound VGPR pressure (<=8 B-frags + 4 accs live at a time).
    #pragma unroll 1
    for (int t = 0; t < 3; ++t) {
        const int nt = wid + t * 8;
        bf16x8 bh[4], bl[4];
        {
            const float* wrow = qkv_w + (nt * 16 + lr) * C + lg * 8;
            #pragma unroll
            for (int ks = 0; ks < 4; ++ks) {
                const float4 f0 = *(const float4*)(wrow + ks * 32);
                const float4 f1 = *(const float4*)(wrow + ks * 32 + 4);
                const float f[8] = {f0.x, f0.y, f0.z, f0.w, f1.x, f1.y, f1.z, f1.w};
                #pragma unroll
                for (int j = 0; j < 8; ++j) {
                    ushort hh, ll; split2(f[j], hh, ll);
                    bh[ks][j] = (short)hh; bl[ks][j] = (short)ll;
                }
            }
        }
        f32x4 acc[4];
        #pragma unroll
        for (int mt = 0; mt < 4; ++mt) acc[mt] = fz;

        #pragma unroll
        for (int ks = 0; ks < 4; ++ks) {
            #pragma unroll
            for (int mt = 0; mt < 4; ++mt) {
                const bf16x8 ah = *(const bf16x8*)(XU + (mt*4+ks)*2048 + lane*16);
                const bf16x8 al = *(const bf16x8*)(XU + (mt*4+ks)*2048 + 1024 + lane*16);
                acc[mt] = mfma16(al, bh[ks], acc[mt]);
                acc[mt] = mfma16(ah, bl[ks], acc[mt]);
                acc[mt] = mfma16(ah, bh[ks], acc[mt]);
            }
        }
        // Scatter D into fragment order. o = output col, n = token row.
        const int o   = nt * 16 + lr;
        const int sec = o >> 7;          // 0=q 1=k 2=v
        const int h   = (o >> 5) & 3;
        const int d   = o & 31;
        #pragma unroll
        for (int mt = 0; mt < 4; ++mt) {
            #pragma unroll
            for (int ri = 0; ri < 4; ++ri) {
                const int n = mt * 16 + lg * 4 + ri;
                float v0 = acc[mt][ri];
                if (sec == 0) v0 *= SCALE;
                ushort hh, ll; split2(v0, hh, ll);
                unsigned char* p;
                if (sec == 0) {        // q: A-frag (row=token, k=d)
                    p = Qr + (h*4+mt)*2048 + ((n & 15) + 16*(d>>3))*16 + (d&7)*2;
                } else if (sec == 1) { // k: B-frag (col=token, k=d)
                    p = Kr + (h*4+mt)*2048 + ((n & 15) + 16*(d>>3))*16 + (d&7)*2;
                } else {               // v: B-frag (col=d, k=token)
                    p = Vr + ((h*2 + (d>>4))*2 + (n>>5))*2048
                          + ((d & 15) + 16*((n&31)>>3))*16 + (n&7)*2;
                }
                *(ushort*)p          = hh;
                *(ushort*)(p + 1024) = ll;
            }
        }
    }
    __syncthreads();

    // ---- Phase 2: scores (MFMA) + bias + mask + in-register softmax ----
    float Pv[2][4][4];
    float pinv[2][4];
    {
        const float* mrow = mask + (size_t)(blk % nW) * (N * N);
        #pragma unroll
        for (int pass = 0; pass < 2; ++pass) {
            const int cb = wid + pass * 8;   // combo = (head, row-tile)
            const int h = cb >> 2, mt = cb & 3;
            const bf16x8 qh = *(const bf16x8*)(Qr + (h*4+mt)*2048 + lane*16);
            const bf16x8 ql = *(const bf16x8*)(Qr + (h*4+mt)*2048 + 1024 + lane*16);
            f32x4 S[4];
            #pragma unroll
            for (int ntt = 0; ntt < 4; ++ntt) {
                const bf16x8 kh = *(const bf16x8*)(Kr + (h*4+ntt)*2048 + lane*16);
                const bf16x8 kl = *(const bf16x8*)(Kr + (h*4+ntt)*2048 + 1024 + lane*16);
                f32x4 a = fz;
                a = mfma16(ql, kh, a);
                a = mfma16(qh, kl, a);
                a = mfma16(qh, kh, a);
                S[ntt] = a;
            }
            // + pos_bias + shift mask; pad cols (m>=49) -> -inf
            #pragma unroll
            for (int ntt = 0; ntt < 4; ++ntt) {
                const int m = ntt * 16 + lr;
                #pragma unroll
                for (int ri = 0; ri < 4; ++ri) {
                    const int n = mt * 16 + lg * 4 + ri;
                    if (m < N) {
                        const int rr = (n < N ? n : N - 1) * N + m;
                        S[ntt][ri] += mrow[rr] + table[pos_index[rr] * 4 + h];
                    } else {
                        S[ntt][ri] = -1e30f;
                    }
                }
            }
            // Row softmax: row n lives in 16 lanes sharing lg (cols = l&15), 4 tiles.
            #pragma unroll
            for (int ri = 0; ri < 4; ++ri) {
                float mx = fmaxf(fmaxf(S[0][ri], S[1][ri]), fmaxf(S[2][ri], S[3][ri]));
                mx = fmaxf(mx, __shfl_xor(mx, 1));
                mx = fmaxf(mx, __shfl_xor(mx, 2));
                mx = fmaxf(mx, __shfl_xor(mx, 4));
                mx = fmaxf(mx, __shfl_xor(mx, 8));
                float sm = 0.f;
                #pragma unroll
                for (int ntt = 0; ntt < 4; ++ntt) {
                    const float e = __expf(S[ntt][ri] - mx);
                    Pv[pass][ntt][ri] = e;
                    sm += e;
                }
                sm += __shfl_xor(sm, 1);
                sm += __shfl_xor(sm, 2);
                sm += __shfl_xor(sm, 4);
                sm += __shfl_xor(sm, 8);
                pinv[pass][ri] = 1.f / sm;
            }
        }
    }
    __syncthreads();   // all q/k fragment reads complete before P overwrites them

    // ---- Phase 2b: write P as A-frags (hi -> Qr, lo -> Kr), and 1/sum ----
    {
        #pragma unroll
        for (int pass = 0; pass < 2; ++pass) {
            const int cb = wid + pass * 8;
            const int h = cb >> 2, mt = cb & 3;
            #pragma unroll
            for (int ntt = 0; ntt < 4; ++ntt) {
                const int m = ntt * 16 + lr;       // k-index (token m)
                #pragma unroll
                for (int ri = 0; ri < 4; ++ri) {
                    const int nl = lg * 4 + ri;    // n & 15
                    ushort hh, ll; split2(Pv[pass][ntt][ri], hh, ll);
                    const int off = ((h*4+mt)*2 + (m>>5))*1024
                                  + (nl + 16*((m&31)>>3))*16 + (m&7)*2;
                    *(ushort*)(Qr + off) = hh;
                    *(ushort*)(Kr + off) = ll;
                }
            }
            if (lr == 0) {
                #pragma unroll
                for (int ri = 0; ri < 4; ++ri)
                    inv_s[h*64 + mt*16 + lg*4 + ri] = pinv[pass][ri];
            }
        }
    }
    __syncthreads();

    // ---- Phase 3: PV (MFMA) -> u-frags in XU ----
    {
        const int h = wid >> 1, dt = wid & 1;    // wave owns (head, d-halftile)
        bf16x8 vh[2], vl[2];
        #pragma unroll
        for (int ks = 0; ks < 2; ++ks) {
            vh[ks] = *(const bf16x8*)(Vr + ((h*2+dt)*2+ks)*2048 + lane*16);
            vl[ks] = *(const bf16x8*)(Vr + ((h*2+dt)*2+ks)*2048 + 1024 + lane*16);
        }
        const int c = h * 32 + dt * 16 + lr;     // output channel
        #pragma unroll
        for (int mt = 0; mt < 4; ++mt) {
            f32x4 a = fz;
            #pragma unroll
            for (int ks = 0; ks < 2; ++ks) {
                const bf16x8 ph = *(const bf16x8*)(Qr + ((h*4+mt)*2+ks)*1024 + lane*16);
                const bf16x8 pl = *(const bf16x8*)(Kr + ((h*4+mt)*2+ks)*1024 + lane*16);
                a = mfma16(pl, vh[ks], a);
                a = mfma16(ph, vl[ks], a);
                a = mfma16(ph, vh[ks], a);
            }
            #pragma unroll
            for (int ri = 0; ri < 4; ++ri) {
                const int n = mt * 16 + lg * 4 + ri;
                const float ov = a[ri] * inv_s[h*64 + n];
                ushort hh, ll; split2(ov, hh, ll);
                unsigned char* p = XU + (mt*4 + (c>>5))*2048
                                 + ((n & 15) + 16*((c&31)>>3))*16 + (c&7)*2;
                *(ushort*)p          = hh;
                *(ushort*)(p + 1024) = ll;
            }
        }
    }
    __syncthreads();

    // ---- Phase 4: proj GEMM [64x128]x[128x128] + bias, store ----
    {
        const int o = wid * 16 + lr;             // wave owns one 16-col tile
        const float* wrow = proj_w + o * C + lg * 8;
        bf16x8 bh[4], bl[4];
        #pragma unroll
        for (int ks = 0; ks < 4; ++ks) {
            const float4 f0 = *(const float4*)(wrow + ks * 32);
            const float4 f1 = *(const float4*)(wrow + ks * 32 + 4);
            const float f[8] = {f0.x, f0.y, f0.z, f0.w, f1.x, f1.y, f1.z, f1.w};
            #pragma unroll
            for (int j = 0; j < 8; ++j) {
                ushort hh, ll; split2(f[j], hh, ll);
                bh[ks][j] = (short)hh; bl[ks][j] = (short)ll;
            }
        }
        f32x4 acc[4];
        #pragma unroll
        for (int mt = 0; mt < 4; ++mt) acc[mt] = fz;
        #pragma unroll
        for (int ks = 0; ks < 4; ++ks) {
            #pragma unroll
            for (int mt = 0; mt < 4; ++mt) {
                const bf16x8 ah = *(const bf16x8*)(XU + (mt*4+ks)*2048 + lane*16);
                const bf16x8 al = *(const bf16x8*)(XU + (mt*4+ks)*2048 + 1024 + lane*16);
                acc[mt] = mfma16(al, bh[ks], acc[mt]);
                acc[mt] = mfma16(ah, bl[ks], acc[mt]);
                acc[mt] = mfma16(ah, bh[ks], acc[mt]);
            }
        }
        const float pb = proj_b[o];
        float* orow = out + (size_t)blk * (N * C);
        #pragma unroll
        for (int mt = 0; mt < 4; ++mt) {
            #pragma unroll
            for (int ri = 0; ri < 4; ++ri) {
                const int n = mt * 16 + lg * 4 + ri;
                if (n < N) orow[n * C + o] = acc[mt][ri] + pb;
            }
        }
    }
}

extern "C" void kernel_launch(void* const* d_in, const int* in_sizes, int n_in,
                              void* d_out, int out_size, void* d_ws, size_t ws_size,
                              hipStream_t stream) {
    const float* x       = (const float*)d_in[0];
    const float* qkv_w   = (const float*)d_in[1];
    const float* proj_w  = (const float*)d_in[2];
    const float* proj_b  = (const float*)d_in[3];
    const float* table   = (const float*)d_in[4];
    const float* mask    = (const float*)d_in[5];
    const int*   pos_idx = (const int*)d_in[6];
    float* out = (float*)d_out;

    const int B  = in_sizes[0] / (N * C);       // in_sizes are element counts
    const int nW = in_sizes[5] / (N * N);

    win_attn<<<B, NT, 0, stream>>>(x, qkv_w, proj_w, proj_b, table, mask, pos_idx, out, nW);
}

// Round 4
// 565.787 us; speedup vs baseline: 4.0801x; 1.7553x over previous
//
#include <hip/hip_runtime.h>
#include <math.h>

// WindowAttention fused kernel, round 4 (= round-3 design, crash fix).
// Round-3 container crash diagnosed as OOB/null writes through d_ws (ws_size
// never checked). All block-invariant prep data now lives in static __device__
// globals; d_ws is unused.
//
// Design (vs round-2 805us):
// - Block-invariant prep (weights -> bf16 hi/lo fragments, pos-bias gather)
//   in a tiny prep kernel, run once per launch.
// - Activations stored bf16 hi-only in LDS (64KB -> 2 blocks/CU); weights keep
//   hi/lo split (error dominated by activation rounding ~2e-3 rel/stage).
// - XU fragment layout XOR-rotate swizzled (phase-0 write was 16-way conflict).
// - All 2B scatter stores pair-packed into 4B stores (shfl_xor lane pairing).
//
// Fragment conventions (sigma-consistent A/B slot->k maps, D per m89):
//   A: row = lane&15, slot(g=lane>>4, j) -> k = 8g+j
//   B: col = lane&15, same slot map
//   D: col = lane&15, row = 4*(lane>>4)+reg
// Unit = 64 lanes x 16B = 1KB.
//
// LDS (65536 B): XU 16K (x-frags -> u-frags) | Qr 16K (q) | Kr 16K (k) |
//                Vr 16K (v-frags); P-frags overwrite Qr+Kr.

namespace {
constexpr int N  = 49;
constexpr int C  = 128;
constexpr int NT = 512;
constexpr float SCALE = 0.17677669529663687f;  // 32^-0.5

typedef short bf16x8 __attribute__((ext_vector_type(8)));
typedef float f32x4  __attribute__((ext_vector_type(4)));
}

// ---- static device storage for block-invariant data (no d_ws dependence) ----
__device__ __align__(16) ushort g_wq_hi[24 * 4 * 512];   //  96 KB qkv W hi-frags
__device__ __align__(16) ushort g_wq_lo[24 * 4 * 512];   //  96 KB qkv W lo-frags
__device__ __align__(16) ushort g_wp_hi[8 * 4 * 512];    //  32 KB proj W hi-frags
__device__ __align__(16) ushort g_wp_lo[8 * 4 * 512];    //  32 KB proj W lo-frags
__device__ __align__(16) float  g_bias[4 * 2401];        //  38 KB pos-bias [h][rr]

__device__ __forceinline__ ushort bf16_rne(float f) {
    unsigned int u = __builtin_bit_cast(unsigned int, f);
    unsigned int r = u + 0x7FFFu + ((u >> 16) & 1u);
    return (ushort)(r >> 16);
}
__device__ __forceinline__ float bf16_to_f(ushort h) {
    unsigned int u = ((unsigned int)h) << 16;
    return __builtin_bit_cast(float, u);
}
__device__ __forceinline__ void split2(float x, ushort& hi, ushort& lo) {
    hi = bf16_rne(x);
    lo = bf16_rne(x - bf16_to_f(hi));
}
__device__ __forceinline__ f32x4 mfma16(bf16x8 a, bf16x8 b, f32x4 c) {
    return __builtin_amdgcn_mfma_f32_16x16x32_bf16(a, b, c, 0, 0, 0);
}
// 16B-slot index within a 1KB unit, XOR-rotate swizzled so that phase-0's
// (same-row, varying g/ks) writes spread across bank groups.
__device__ __forceinline__ int idx16(int row, int g, int ks) {
    return ((row + 4 * g + ks) & 15) + 16 * g;
}

// ---- prep kernel: block-invariant conversions ----
__global__ void prep(const float* __restrict__ qkv_w, const float* __restrict__ proj_w,
                     const float* __restrict__ table, const int* __restrict__ pos_index)
{
    const int i = blockIdx.x * 256 + threadIdx.x;
    if (i < 24 * 4 * 512) {   // qkv B-frags
        const int unit = i >> 9, sl = i & 511;
        const int nt = unit >> 2, ks = unit & 3;
        const int lane = sl >> 3, j = sl & 7;
        const float w = qkv_w[(nt * 16 + (lane & 15)) * C + ks * 32 + (lane >> 4) * 8 + j];
        ushort hi, lo; split2(w, hi, lo);
        g_wq_hi[i] = hi; g_wq_lo[i] = lo;
    }
    if (i < 8 * 4 * 512) {    // proj B-frags
        const int unit = i >> 9, sl = i & 511;
        const int nt = unit >> 2, ks = unit & 3;
        const int lane = sl >> 3, j = sl & 7;
        const float w = proj_w[(nt * 16 + (lane & 15)) * C + ks * 32 + (lane >> 4) * 8 + j];
        ushort hi, lo; split2(w, hi, lo);
        g_wp_hi[i] = hi; g_wp_lo[i] = lo;
    }
    if (i < 4 * 2401) {       // bias[h][rr] = table[pos_index[rr]*4 + h]
        g_bias[i] = table[pos_index[i % 2401] * 4 + (i / 2401)];
    }
}

__global__ __launch_bounds__(NT, 4) void win_attn(
    const float* __restrict__ x,         // [B,49,128]
    const float* __restrict__ proj_b,    // [128]
    const float* __restrict__ mask,      // [nW,49,49]
    float* __restrict__ out,             // [B,49,128]
    int nW)
{
    __shared__ __align__(16) unsigned char smem[65536];
    unsigned char* const XU = smem;            // 16KB x-frags -> u-frags
    unsigned char* const Qr = smem + 16384;    // 16KB q-frags
    unsigned char* const Kr = smem + 32768;    // 16KB k-frags
    unsigned char* const Vr = smem + 49152;    // 16KB v-frags
    unsigned char* const Pr = smem + 16384;    // 32KB P-frags (over Qr+Kr)

    const int tid  = threadIdx.x;
    const int blk  = blockIdx.x;
    const int lane = tid & 63;
    const int wid  = tid >> 6;
    const int lr   = lane & 15;
    const int lg   = lane >> 4;
    const f32x4 fz = {0.f, 0.f, 0.f, 0.f};

    // ---- Phase 0: x -> A-frags (bf16 hi), rows 49..63 zero ----
    {
        const float* xb = x + (size_t)blk * (N * C);
        #pragma unroll
        for (int it = 0; it < 2; ++it) {
            const int slot = tid + it * NT;   // (n 0..63) x (chunk 0..15)
            const int n  = slot >> 4;
            const int cc = slot & 15;
            const int s  = cc >> 2;           // ks
            const int g  = cc & 3;            // k-group
            unsigned int h32[4];
            if (n < N) {
                const float4 f0 = *(const float4*)(xb + n * C + cc * 8);
                const float4 f1 = *(const float4*)(xb + n * C + cc * 8 + 4);
                const float f[8] = {f0.x, f0.y, f0.z, f0.w, f1.x, f1.y, f1.z, f1.w};
                #pragma unroll
                for (int j = 0; j < 4; ++j)
                    h32[j] = (unsigned int)bf16_rne(f[2*j])
                           | ((unsigned int)bf16_rne(f[2*j+1]) << 16);
            } else {
                #pragma unroll
                for (int j = 0; j < 4; ++j) h32[j] = 0u;
            }
            unsigned char* p = XU + ((n >> 4) * 4 + s) * 1024 + idx16(n & 15, g, s) * 16;
            *(uint4*)p = make_uint4(h32[0], h32[1], h32[2], h32[3]);
        }
    }
    __syncthreads();

    // ---- Phase 1: qkv GEMM; A = x_hi, B = W hi/lo (2 MFMA/product) ----
    #pragma unroll 1
    for (int t = 0; t < 3; ++t) {
        const int nt = wid + t * 8;
        bf16x8 bh[4], bl[4];
        #pragma unroll
        for (int ks = 0; ks < 4; ++ks) {
            bh[ks] = *(const bf16x8*)(g_wq_hi + (nt * 4 + ks) * 512 + lane * 8);
            bl[ks] = *(const bf16x8*)(g_wq_lo + (nt * 4 + ks) * 512 + lane * 8);
        }
        f32x4 acc[4];
        #pragma unroll
        for (int mt = 0; mt < 4; ++mt) acc[mt] = fz;
        #pragma unroll
        for (int ks = 0; ks < 4; ++ks) {
            #pragma unroll
            for (int mt = 0; mt < 4; ++mt) {
                const bf16x8 ah = *(const bf16x8*)(XU + (mt * 4 + ks) * 1024
                                                      + idx16(lr, lg, ks) * 16);
                acc[mt] = mfma16(ah, bl[ks], acc[mt]);
                acc[mt] = mfma16(ah, bh[ks], acc[mt]);
            }
        }
        // scatter D into q/k/v frag order (pair-packed 4B stores)
        const int o   = nt * 16 + lr;
        const int sec = o >> 7;          // 0=q 1=k 2=v (wave-uniform)
        const int h   = (o >> 5) & 3;
        const int d   = o & 31;
        #pragma unroll
        for (int mt = 0; mt < 4; ++mt) {
            unsigned int hh[4];
            #pragma unroll
            for (int ri = 0; ri < 4; ++ri) {
                float v0 = acc[mt][ri];
                if (sec == 0) v0 *= SCALE;
                hh[ri] = (unsigned int)bf16_rne(v0);
            }
            if (sec <= 1) {
                unsigned char* ubase = (sec == 0 ? Qr : Kr) + (h * 4 + mt) * 1024;
                #pragma unroll
                for (int ri = 0; ri < 4; ++ri) {
                    const unsigned int part = __shfl_xor(hh[ri], 1);
                    if (!(lane & 1)) {
                        const int n = mt * 16 + lg * 4 + ri;
                        *(unsigned int*)(ubase + ((n & 15) + 16 * (d >> 3)) * 16
                                               + (d & 7) * 2) = hh[ri] | (part << 16);
                    }
                }
            } else {
                #pragma unroll
                for (int rp = 0; rp < 2; ++rp) {   // pack (ri, ri+1): adjacent k=n
                    const int n = mt * 16 + lg * 4 + rp * 2;
                    const int u = (h * 2 + (d >> 4)) * 2 + (n >> 5);
                    *(unsigned int*)(Vr + u * 1024 + ((d & 15) + 16 * ((n & 31) >> 3)) * 16
                                        + (n & 7) * 2) = hh[rp*2] | (hh[rp*2+1] << 16);
                }
            }
        }
    }
    __syncthreads();

    // ---- Phase 2: scores (1 MFMA/tile) + bias + mask + in-register softmax ----
    float Ps[2][4][4];
    {
        const float* mrow = mask + (size_t)(blk % nW) * (N * N);
        #pragma unroll
        for (int pass = 0; pass < 2; ++pass) {
            const int cb = wid + pass * 8;   // (head, row-tile)
            const int h = cb >> 2, mt = cb & 3;
            const bf16x8 qh = *(const bf16x8*)(Qr + (h * 4 + mt) * 1024 + lane * 16);
            f32x4 S[4];
            #pragma unroll
            for (int ntt = 0; ntt < 4; ++ntt) {
                const bf16x8 kh = *(const bf16x8*)(Kr + (h * 4 + ntt) * 1024 + lane * 16);
                S[ntt] = mfma16(qh, kh, fz);
            }
            #pragma unroll
            for (int ntt = 0; ntt < 4; ++ntt) {
                const int m = ntt * 16 + lr;
                #pragma unroll
                for (int ri = 0; ri < 4; ++ri) {
                    const int n = mt * 16 + lg * 4 + ri;
                    if (m < N) {
                        const int rr = (n < N ? n : N - 1) * N + m;
                        S[ntt][ri] += mrow[rr] + g_bias[h * 2401 + rr];
                    } else {
                        S[ntt][ri] = -1e30f;
                    }
                }
            }
            #pragma unroll
            for (int ri = 0; ri < 4; ++ri) {
                float mx = fmaxf(fmaxf(S[0][ri], S[1][ri]), fmaxf(S[2][ri], S[3][ri]));
                mx = fmaxf(mx, __shfl_xor(mx, 1));
                mx = fmaxf(mx, __shfl_xor(mx, 2));
                mx = fmaxf(mx, __shfl_xor(mx, 4));
                mx = fmaxf(mx, __shfl_xor(mx, 8));
                float sm = 0.f;
                #pragma unroll
                for (int ntt = 0; ntt < 4; ++ntt) {
                    const float e = __expf(S[ntt][ri] - mx);
                    Ps[pass][ntt][ri] = e;
                    sm += e;
                }
                sm += __shfl_xor(sm, 1);
                sm += __shfl_xor(sm, 2);
                sm += __shfl_xor(sm, 4);
                sm += __shfl_xor(sm, 8);
                const float pinv = 1.f / sm;   // fold 1/sum into P now
                #pragma unroll
                for (int ntt = 0; ntt < 4; ++ntt) Ps[pass][ntt][ri] *= pinv;
            }
        }
    }
    __syncthreads();   // q/k reads done before P overwrites

    // ---- Phase 2b: write normalized P as A-frags over Qr+Kr ----
    {
        #pragma unroll
        for (int pass = 0; pass < 2; ++pass) {
            const int cb = wid + pass * 8;
            const int h = cb >> 2, mt = cb & 3;
            #pragma unroll
            for (int ntt = 0; ntt < 4; ++ntt) {
                const int m = ntt * 16 + lr;   // k-index
                #pragma unroll
                for (int ri = 0; ri < 4; ++ri) {
                    const unsigned int hh = (unsigned int)bf16_rne(Ps[pass][ntt][ri]);
                    const unsigned int part = __shfl_xor(hh, 1);
                    if (!(lane & 1)) {
                        const int nl = lg * 4 + ri;
                        const int off = ((h * 4 + mt) * 2 + (m >> 5)) * 1024
                                      + (nl + 16 * ((m & 31) >> 3)) * 16 + (m & 7) * 2;
                        *(unsigned int*)(Pr + off) = hh | (part << 16);
                    }
                }
            }
        }
    }
    __syncthreads();

    // ---- Phase 3: PV (1 MFMA/tile) -> u-frags in XU (swizzled) ----
    {
        const int h = wid >> 1, dt = wid & 1;
        bf16x8 vh[2];
        #pragma unroll
        for (int ks = 0; ks < 2; ++ks)
            vh[ks] = *(const bf16x8*)(Vr + ((h * 2 + dt) * 2 + ks) * 1024 + lane * 16);
        const int c = h * 32 + dt * 16 + lr;   // output channel
        #pragma unroll
        for (int mt = 0; mt < 4; ++mt) {
            f32x4 a = fz;
            #pragma unroll
            for (int ks = 0; ks < 2; ++ks) {
                const bf16x8 ph = *(const bf16x8*)(Pr + ((h * 4 + mt) * 2 + ks) * 1024
                                                      + lane * 16);
                a = mfma16(ph, vh[ks], a);
            }
            #pragma unroll
            for (int ri = 0; ri < 4; ++ri) {
                const unsigned int hh = (unsigned int)bf16_rne(a[ri]);
                const unsigned int part = __shfl_xor(hh, 1);
                if (!(lane & 1)) {
                    const int n = mt * 16 + lg * 4 + ri;
                    unsigned char* p = XU + (mt * 4 + (c >> 5)) * 1024
                                     + idx16(n & 15, (c & 31) >> 3, c >> 5) * 16
                                     + (c & 7) * 2;
                    *(unsigned int*)p = hh | (part << 16);
                }
            }
        }
    }
    __syncthreads();

    // ---- Phase 4: proj GEMM; A = u_hi, B = W hi/lo; + bias; store ----
    {
        const int o = wid * 16 + lr;
        bf16x8 bh[4], bl[4];
        #pragma unroll
        for (int ks = 0; ks < 4; ++ks) {
            bh[ks] = *(const bf16x8*)(g_wp_hi + (wid * 4 + ks) * 512 + lane * 8);
            bl[ks] = *(const bf16x8*)(g_wp_lo + (wid * 4 + ks) * 512 + lane * 8);
        }
        f32x4 acc[4];
        #pragma unroll
        for (int mt = 0; mt < 4; ++mt) acc[mt] = fz;
        #pragma unroll
        for (int ks = 0; ks < 4; ++ks) {
            #pragma unroll
            for (int mt = 0; mt < 4; ++mt) {
                const bf16x8 ah = *(const bf16x8*)(XU + (mt * 4 + ks) * 1024
                                                      + idx16(lr, lg, ks) * 16);
                acc[mt] = mfma16(ah, bl[ks], acc[mt]);
                acc[mt] = mfma16(ah, bh[ks], acc[mt]);
            }
        }
        const float pb = proj_b[o];
        float* orow = out + (size_t)blk * (N * C);
        #pragma unroll
        for (int mt = 0; mt < 4; ++mt) {
            #pragma unroll
            for (int ri = 0; ri < 4; ++ri) {
                const int n = mt * 16 + lg * 4 + ri;
                if (n < N) orow[n * C + o] = acc[mt][ri] + pb;
            }
        }
    }
}

extern "C" void kernel_launch(void* const* d_in, const int* in_sizes, int n_in,
                              void* d_out, int out_size, void* d_ws, size_t ws_size,
                              hipStream_t stream) {
    const float* x       = (const float*)d_in[0];
    const float* qkv_w   = (const float*)d_in[1];
    const float* proj_w  = (const float*)d_in[2];
    const float* proj_b  = (const float*)d_in[3];
    const float* table   = (const float*)d_in[4];
    const float* mask    = (const float*)d_in[5];
    const int*   pos_idx = (const int*)d_in[6];
    float* out = (float*)d_out;
    (void)d_ws; (void)ws_size;

    const int B  = in_sizes[0] / (N * C);       // element counts
    const int nW = in_sizes[5] / (N * N);

    prep<<<192, 256, 0, stream>>>(qkv_w, proj_w, table, pos_idx);
    win_attn<<<B, NT, 0, stream>>>(x, proj_b, mask, out, nW);
}